// Round 1
// baseline (417.226 us; speedup 1.0000x reference)
//
#include <hip/hip_runtime.h>
#include <cfloat>

#define B_ 32
#define N_ 4096
#define C_ 768
#define T_ 1000
#define K_ 20

#define PHC 32            // floats per c-phase
#define NPH (C_/PHC)      // 24 phases
#define PXB 128           // pixels per k2 block
#define GAP_TH 1e-3f
#define MAXF 16384

// ---------------- K1a: vg_logit in fp64 (+ zero counters) ----------------
__global__ __launch_bounds__(256) void k1_logits(const float* __restrict__ g_feat,
                                                 const float* __restrict__ text,
                                                 double* __restrict__ logits,
                                                 int* __restrict__ cnt,
                                                 int* __restrict__ flagcnt) {
    int b = blockIdx.x;
    int wid = threadIdx.x >> 6, lane = threadIdx.x & 63;
    int t = blockIdx.y * 4 + wid;           // grid.y = 250 -> t in [0,1000)
    if (b == 0 && blockIdx.y == 0) {
        for (int i = threadIdx.x; i < B_ * K_; i += 256) cnt[i] = 0;
        if (threadIdx.x == 0) flagcnt[0] = 0;
    }
    const float* g = g_feat + b * C_;
    const float* e = text + t * C_;
    double s = 0.0;
    #pragma unroll
    for (int j = 0; j < 12; ++j) {
        int c = lane + 64 * j;
        s += (double)g[c] * (double)e[c];
    }
    #pragma unroll
    for (int m = 32; m; m >>= 1) s += __shfl_xor(s, m);
    if (lane == 0) logits[b * T_ + t] = s;
}

// ---------------- K1b: top-20 per batch + gather embeddings ----------------
__global__ __launch_bounds__(256) void k1b_topk(const double* __restrict__ logits,
                                                const float* __restrict__ text,
                                                float* __restrict__ agg,
                                                int* __restrict__ sel) {
    __shared__ double ll[T_];
    __shared__ double rv[256];
    __shared__ int    ri[256];
    __shared__ int    ssel[K_];
    int b = blockIdx.x, tid = threadIdx.x;
    for (int t = tid; t < T_; t += 256) ll[t] = logits[b * T_ + t];
    __syncthreads();
    for (int j = 0; j < K_; ++j) {
        double bv = -DBL_MAX; int bi = 0;
        for (int t = tid; t < T_; t += 256) {
            double v = ll[t];
            if (v > bv) { bv = v; bi = t; }
        }
        rv[tid] = bv; ri[tid] = bi;
        __syncthreads();
        for (int s = 128; s; s >>= 1) {
            if (tid < s) {
                double ov = rv[tid + s]; int oi = ri[tid + s];
                if (ov > rv[tid] || (ov == rv[tid] && oi < ri[tid])) { rv[tid] = ov; ri[tid] = oi; }
            }
            __syncthreads();
        }
        if (tid == 0) { ssel[j] = ri[0]; ll[ri[0]] = -DBL_MAX; }
        __syncthreads();
    }
    if (tid < K_) sel[b * K_ + tid] = ssel[tid];
    for (int i = tid; i < K_ * C_; i += 256) {
        int j = i / C_, c = i - j * C_;
        agg[b * K_ * C_ + i] = text[ssel[j] * C_ + c];
    }
}

// ---------------- K2: per-pixel argmax over 20 dots (fp32 + gap flag) ----------------
__global__ __launch_bounds__(128) void k2_argmax(const float* __restrict__ feat,
                                                 const float* __restrict__ agg,
                                                 int* __restrict__ kidx,
                                                 int* __restrict__ cnt,
                                                 int* __restrict__ flagcnt,
                                                 int* __restrict__ flaglist) {
    __shared__ float sbuf[2][PXB * PHC];    // 2 x 16 KB, XOR-swizzled slots
    __shared__ int scnt[K_];
    int bx = blockIdx.x;
    int b = bx >> 5, tile = bx & 31;
    int n0 = tile * PXB;
    int wid = threadIdx.x >> 6, lane = threadIdx.x & 63;
    if (threadIdx.x < K_) scnt[threadIdx.x] = 0;

    const float* fb = feat + ((size_t)b * N_ + n0) * C_;
    const float* eb = agg + b * (K_ * C_);

    int rsub = lane >> 3;       // row within 8-row group
    int slot = lane & 7;

    auto stage = [&](int p, int s) {
        int c0 = p * PHC;
        float* dst0 = &sbuf[s][(wid * 64) * PHC];
        #pragma unroll
        for (int i = 0; i < 8; ++i) {
            int row = i * 8 + rsub;                    // row within this wave's 64
            int c4 = slot ^ rsub;                      // swizzled source chunk
            const float* g = fb + ((size_t)(wid * 64 + row) * C_ + c0 + 4 * c4);
            float* d = dst0 + i * 8 * PHC;             // wave-uniform LDS base; HW adds lane*16
            __builtin_amdgcn_global_load_lds((const __attribute__((address_space(1))) void*)g,
                                             (__attribute__((address_space(3))) void*)d, 16, 0, 0);
        }
    };

    float acc[K_];
    #pragma unroll
    for (int k = 0; k < K_; ++k) acc[k] = 0.f;

    stage(0, 0);
    __syncthreads();

    int r = wid * 64 + lane;            // my pixel row in tile
    const float* myrow = &sbuf[0][0];   // re-derived per phase below
    (void)myrow;
    for (int p = 0; p < NPH; ++p) {
        int s = p & 1;
        if (p + 1 < NPH) stage(p + 1, s ^ 1);
        const float* rowp = &sbuf[s][r * PHC];
        float4 f[8];
        #pragma unroll
        for (int j = 0; j < 8; ++j) {
            int sl = j ^ (lane & 7);
            f[j] = *(const float4*)(rowp + 4 * sl);
        }
        int c0 = p * PHC;
        #pragma unroll
        for (int k = 0; k < K_; ++k) {
            const float4* e4 = (const float4*)(eb + k * C_ + c0);   // wave-uniform -> s_load
            float a = acc[k];
            #pragma unroll
            for (int j = 0; j < 8; ++j) {
                float4 e = e4[j];
                a = fmaf(f[j].x, e.x, a);
                a = fmaf(f[j].y, e.y, a);
                a = fmaf(f[j].z, e.z, a);
                a = fmaf(f[j].w, e.w, a);
            }
            acc[k] = a;
        }
        __syncthreads();
    }

    // top-2 scan, first-max-wins (matches jnp.argmax)
    float m1 = acc[0]; int i1 = 0; float m2 = -FLT_MAX;
    #pragma unroll
    for (int k = 1; k < K_; ++k) {
        float v = acc[k];
        if (v > m1) { m2 = m1; m1 = v; i1 = k; }
        else if (v > m2) m2 = v;
    }
    int n = n0 + r;
    kidx[b * N_ + n] = i1;
    atomicAdd(&scnt[i1], 1);
    if (m1 - m2 < GAP_TH) {
        int pos = atomicAdd(flagcnt, 1);
        if (pos < MAXF) flaglist[pos] = b * N_ + n;
    }
    __syncthreads();
    if (threadIdx.x < K_) atomicAdd(&cnt[b * K_ + threadIdx.x], scnt[threadIdx.x]);
}

// ---------------- K2.5: fp64 re-decision for knife-edge pixels ----------------
__global__ __launch_bounds__(256) void k25_refine(const float* __restrict__ feat,
                                                  const float* __restrict__ agg,
                                                  int* __restrict__ kidx,
                                                  int* __restrict__ cnt,
                                                  const int* __restrict__ flagcnt,
                                                  const int* __restrict__ flaglist) {
    int wid = threadIdx.x >> 6, lane = threadIdx.x & 63;
    int wg = blockIdx.x * 4 + wid;
    int nf = flagcnt[0]; if (nf > MAXF) nf = MAXF;
    for (int e = wg; e < nf; e += gridDim.x * 4) {
        int pix = flaglist[e];
        int b = pix >> 12;
        const float* fr = feat + (size_t)pix * C_;
        const float* ebase = agg + b * K_ * C_;
        double fd[12];
        #pragma unroll
        for (int j = 0; j < 12; ++j) fd[j] = (double)fr[lane + 64 * j];
        double best = -DBL_MAX; int bi = 0;
        for (int k = 0; k < K_; ++k) {
            const float* er = ebase + k * C_;
            double s = 0.0;
            #pragma unroll
            for (int j = 0; j < 12; ++j) s += fd[j] * (double)er[lane + 64 * j];
            #pragma unroll
            for (int m = 32; m; m >>= 1) s += __shfl_xor(s, m);
            if (s > best) { best = s; bi = k; }
        }
        if (lane == 0) {
            int old = kidx[pix];
            if (old != bi) {
                kidx[pix] = bi;
                atomicSub(&cnt[b * K_ + old], 1);
                atomicAdd(&cnt[b * K_ + bi], 1);
            }
        }
    }
}

// ---------------- K4: broadcast-write output ----------------
__global__ __launch_bounds__(256) void k4_out(const float* __restrict__ agg,
                                              const int* __restrict__ cnt,
                                              const int* __restrict__ kidx,
                                              float* __restrict__ out) {
    int wid = threadIdx.x >> 6, lane = threadIdx.x & 63;
    int wg = blockIdx.x * 4 + wid;          // 8192 waves, 16 px each
    const float4* agg4 = (const float4*)agg;
    float4* out4 = (float4*)out;
    for (int i = 0; i < 16; ++i) {
        int pix = wg * 16 + i;
        int b = pix >> 12;
        int kk = kidx[pix];
        float sc = 1.0f / ((float)cnt[b * K_ + kk] + 1.0f);   // exact int -> correctly-rounded div, matches ref
        const float4* a4 = agg4 + (size_t)(b * K_ + kk) * (C_ / 4);
        float4* o4 = out4 + (size_t)pix * (C_ / 4);
        #pragma unroll
        for (int j = 0; j < 3; ++j) {
            float4 v = a4[lane + 64 * j];
            v.x *= sc; v.y *= sc; v.z *= sc; v.w *= sc;
            o4[lane + 64 * j] = v;
        }
    }
}

extern "C" void kernel_launch(void* const* d_in, const int* in_sizes, int n_in,
                              void* d_out, int out_size, void* d_ws, size_t ws_size,
                              hipStream_t stream) {
    const float* g_feat = (const float*)d_in[0];
    const float* feat   = (const float*)d_in[1];
    // d_in[2] = tau: positive scale, numerically irrelevant (attn == y_hard exactly)
    const float* text   = (const float*)d_in[3];
    float* out = (float*)d_out;

    char* ws = (char*)d_ws;
    double* logits = (double*)(ws + 0);              // 256000 B
    float*  agg    = (float*) (ws + 262144);         // 1966080 B
    int*    sel    = (int*)   (ws + 2228224);        // 2560 B
    int*    cnt    = (int*)   (ws + 2230784);        // 2560 B
    int*    flagc  = (int*)   (ws + 2233344);        // 64 B
    int*    flagl  = (int*)   (ws + 2233408);        // 65536 B
    int*    kidx   = (int*)   (ws + 2301504);        // 524288 B

    k1_logits<<<dim3(32, 250), 256, 0, stream>>>(g_feat, text, logits, cnt, flagc);
    k1b_topk<<<32, 256, 0, stream>>>(logits, text, agg, sel);
    k2_argmax<<<32 * 32, 128, 0, stream>>>(feat, agg, kidx, cnt, flagc, flagl);
    k25_refine<<<64, 256, 0, stream>>>(feat, agg, kidx, cnt, flagc, flagl);
    k4_out<<<2048, 256, 0, stream>>>(agg, cnt, kidx, out);
}

// Round 3
// 304.403 us; speedup vs baseline: 1.3706x; 1.3706x over previous
//
#include <hip/hip_runtime.h>
#include <cfloat>

#define B_ 32
#define N_ 4096
#define C_ 768
#define T_ 1000
#define K_ 20

#define PXB 256           // pixels per k2 block (== threads)
#define PHC 32            // floats per c-phase
#define NPH (C_/PHC)      // 24 phases
#define ECH 160           // 16B chunks of e per phase (20*32*4/16)
#define EPADC 184         // padded chunk count (3 waves x 40 + 64 reach)
#define GAP_TH 1e-3f
#define MAXF 16384

typedef float f32x4 __attribute__((ext_vector_type(4)));

// ---------------- K1a: vg_logit in fp64 (+ zero counters) ----------------
__global__ __launch_bounds__(256) void k1_logits(const float* __restrict__ g_feat,
                                                 const float* __restrict__ text,
                                                 double* __restrict__ logits,
                                                 int* __restrict__ cnt,
                                                 int* __restrict__ flagcnt) {
    int b = blockIdx.x;
    int wid = threadIdx.x >> 6, lane = threadIdx.x & 63;
    int t = blockIdx.y * 4 + wid;           // grid.y = 250 -> t in [0,1000)
    if (b == 0 && blockIdx.y == 0) {
        for (int i = threadIdx.x; i < B_ * K_; i += 256) cnt[i] = 0;
        if (threadIdx.x == 0) flagcnt[0] = 0;
    }
    const float* g = g_feat + b * C_;
    const float* e = text + t * C_;
    double s = 0.0;
    #pragma unroll
    for (int j = 0; j < 12; ++j) {
        int c = lane + 64 * j;
        s += (double)g[c] * (double)e[c];
    }
    #pragma unroll
    for (int m = 32; m; m >>= 1) s += __shfl_xor(s, m);
    if (lane == 0) logits[b * T_ + t] = s;
}

// ---------------- K1b: top-20 per batch + gather embeddings ----------------
__global__ __launch_bounds__(256) void k1b_topk(const double* __restrict__ logits,
                                                const float* __restrict__ text,
                                                float* __restrict__ agg,
                                                int* __restrict__ sel) {
    __shared__ double ll[T_];
    __shared__ double rv[256];
    __shared__ int    ri[256];
    __shared__ int    ssel[K_];
    int b = blockIdx.x, tid = threadIdx.x;
    for (int t = tid; t < T_; t += 256) ll[t] = logits[b * T_ + t];
    __syncthreads();
    for (int j = 0; j < K_; ++j) {
        double bv = -DBL_MAX; int bi = 0;
        for (int t = tid; t < T_; t += 256) {
            double v = ll[t];
            if (v > bv) { bv = v; bi = t; }
        }
        rv[tid] = bv; ri[tid] = bi;
        __syncthreads();
        for (int s = 128; s; s >>= 1) {
            if (tid < s) {
                double ov = rv[tid + s]; int oi = ri[tid + s];
                if (ov > rv[tid] || (ov == rv[tid] && oi < ri[tid])) { rv[tid] = ov; ri[tid] = oi; }
            }
            __syncthreads();
        }
        if (tid == 0) { ssel[j] = ri[0]; ll[ri[0]] = -DBL_MAX; }
        __syncthreads();
    }
    if (tid < K_) sel[b * K_ + tid] = ssel[tid];
    for (int i = tid; i < K_ * C_; i += 256) {
        int j = i / C_, c = i - j * C_;
        agg[b * K_ * C_ + i] = text[ssel[j] * C_ + c];
    }
}

// ---------------- K2: per-pixel argmax, pipelined LDS staging ----------------
// 256 threads = 4 waves; 256 pixels/block; per phase: 8 f-loads + 1 e-load per
// wave via global_load_lds; counted s_waitcnt vmcnt(9) + raw s_barrier keeps
// next-phase loads in flight across barriers (T3/T4).
__global__ __launch_bounds__(256) void k2_argmax(const float* __restrict__ feat,
                                                 const float* __restrict__ agg,
                                                 int* __restrict__ kidx,
                                                 int* __restrict__ cnt,
                                                 int* __restrict__ flagcnt,
                                                 int* __restrict__ flaglist) {
    __shared__ float fbuf[2][PXB * PHC];      // 2 x 32 KB, XOR-swizzled chunk slots
    __shared__ float ebuf[2][EPADC * 4];      // 2 x 2944 B
    __shared__ int scnt[K_];
    int bx = blockIdx.x;
    int b = bx >> 4, tile = bx & 15;
    int n0 = tile * PXB;
    int tid = threadIdx.x, wid = tid >> 6, lane = tid & 63;
    if (tid < K_) scnt[tid] = 0;
    __syncthreads();                          // scnt visible before epilogue atomics

    const float* fb = feat + ((size_t)b * N_ + n0) * C_;
    const float* eb = agg + b * (K_ * C_);

    int rsub = lane >> 3;        // 0..7: row within 8-row group
    int slot = lane & 7;         // 0..7: 16B slot position within row
    int ec = wid * 40 + lane;    // e chunk this lane stages (dup/clamp at tail)
    int ecc = ec < ECH ? ec : (ECH - 1);
    const float* esrc_base = eb + (ecc >> 3) * C_ + 4 * (ecc & 7);

    auto stage = [&](int p, int s) {
        int c0 = p * PHC;
        // f: wave w inst i covers rows w*64 + i*8 + rsub; slot holds chunk slot^rsub
        #pragma unroll
        for (int i = 0; i < 8; ++i) {
            int row = wid * 64 + i * 8 + rsub;
            const float* g = fb + ((size_t)row * C_ + c0 + 4 * (slot ^ rsub));
            float* d = &fbuf[s][(wid * 64 + i * 8) * PHC];   // wave-uniform; HW adds lane*16
            __builtin_amdgcn_global_load_lds((const __attribute__((address_space(1))) void*)g,
                                             (__attribute__((address_space(3))) void*)d, 16, 0, 0);
        }
        // e: 160 chunks, wave w covers chunks [w*40, w*40+64) (overlap dups harmless)
        {
            const float* g = esrc_base + c0;
            float* d = &ebuf[s][wid * 40 * 4];               // wave-uniform; HW adds lane*16
            __builtin_amdgcn_global_load_lds((const __attribute__((address_space(1))) void*)g,
                                             (__attribute__((address_space(3))) void*)d, 16, 0, 0);
        }
    };

    float acc[K_];
    #pragma unroll
    for (int k = 0; k < K_; ++k) acc[k] = 0.f;

    stage(0, 0);

    int r7 = tid & 7;
    #pragma unroll 1
    for (int p = 0; p < NPH; ++p) {
        int s = p & 1;
        if (p + 1 < NPH) {
            stage(p + 1, s ^ 1);
            asm volatile("s_waitcnt vmcnt(9)" ::: "memory");   // phase p's 9 loads done
        } else {
            asm volatile("s_waitcnt vmcnt(0)" ::: "memory");
        }
        asm volatile("s_barrier" ::: "memory");                // phase p ready, no drain

        const float* rowp = &fbuf[s][tid * PHC];
        f32x4 f[8];
        #pragma unroll
        for (int j = 0; j < 8; ++j)
            f[j] = *(const f32x4*)(rowp + 4 * (j ^ r7));
        const float* ep = &ebuf[s][0];
        #pragma unroll
        for (int k = 0; k < K_; ++k) {
            float a = acc[k];
            #pragma unroll
            for (int j = 0; j < 8; ++j) {
                f32x4 e = *(const f32x4*)(ep + k * PHC + 4 * j);  // broadcast ds_read
                a = fmaf(f[j].x, e.x, a);
                a = fmaf(f[j].y, e.y, a);
                a = fmaf(f[j].z, e.z, a);
                a = fmaf(f[j].w, e.w, a);
            }
            acc[k] = a;
        }
        asm volatile("s_barrier" ::: "memory");                // protect buf before overwrite
    }

    // top-2 scan, first-max-wins (matches jnp.argmax)
    float m1 = acc[0]; int i1 = 0; float m2 = -FLT_MAX;
    #pragma unroll
    for (int k = 1; k < K_; ++k) {
        float v = acc[k];
        if (v > m1) { m2 = m1; m1 = v; i1 = k; }
        else if (v > m2) m2 = v;
    }
    int n = n0 + tid;
    kidx[b * N_ + n] = i1;
    atomicAdd(&scnt[i1], 1);
    if (m1 - m2 < GAP_TH) {
        int pos = atomicAdd(flagcnt, 1);
        if (pos < MAXF) flaglist[pos] = b * N_ + n;
    }
    __syncthreads();
    if (tid < K_) atomicAdd(&cnt[b * K_ + tid], scnt[tid]);
}

// ---------------- K2.5: fp64 re-decision for knife-edge pixels ----------------
__global__ __launch_bounds__(256) void k25_refine(const float* __restrict__ feat,
                                                  const float* __restrict__ agg,
                                                  int* __restrict__ kidx,
                                                  int* __restrict__ cnt,
                                                  const int* __restrict__ flagcnt,
                                                  const int* __restrict__ flaglist) {
    int wid = threadIdx.x >> 6, lane = threadIdx.x & 63;
    int wg = blockIdx.x * 4 + wid;
    int nf = flagcnt[0]; if (nf > MAXF) nf = MAXF;
    for (int e = wg; e < nf; e += gridDim.x * 4) {
        int pix = flaglist[e];
        int b = pix >> 12;
        const float* fr = feat + (size_t)pix * C_;
        const float* ebase = agg + b * K_ * C_;
        double fd[12];
        #pragma unroll
        for (int j = 0; j < 12; ++j) fd[j] = (double)fr[lane + 64 * j];
        double best = -DBL_MAX; int bi = 0;
        for (int k = 0; k < K_; ++k) {
            const float* er = ebase + k * C_;
            double s = 0.0;
            #pragma unroll
            for (int j = 0; j < 12; ++j) s += fd[j] * (double)er[lane + 64 * j];
            #pragma unroll
            for (int m = 32; m; m >>= 1) s += __shfl_xor(s, m);
            if (s > best) { best = s; bi = k; }
        }
        if (lane == 0) {
            int old = kidx[pix];
            if (old != bi) {
                kidx[pix] = bi;
                atomicSub(&cnt[b * K_ + old], 1);
                atomicAdd(&cnt[b * K_ + bi], 1);
            }
        }
    }
}

// ---------------- K4: broadcast-write output ----------------
__global__ __launch_bounds__(256) void k4_out(const float* __restrict__ agg,
                                              const int* __restrict__ cnt,
                                              const int* __restrict__ kidx,
                                              float* __restrict__ out) {
    int wid = threadIdx.x >> 6, lane = threadIdx.x & 63;
    int wg = blockIdx.x * 4 + wid;          // 8192 waves, 16 px each
    int base = wg * 16;
    int b = base >> 12;                     // wave-uniform (16 | 4096)
    int kk[16];
    #pragma unroll
    for (int i = 0; i < 16; ++i) kk[i] = kidx[base + i];
    float sc[16];
    #pragma unroll
    for (int i = 0; i < 16; ++i) sc[i] = 1.0f / ((float)cnt[b * K_ + kk[i]] + 1.0f);
    const f32x4* agg4 = (const f32x4*)agg;
    f32x4* out4 = (f32x4*)out;
    #pragma unroll
    for (int i = 0; i < 16; ++i) {
        const f32x4* a4 = agg4 + (size_t)(b * K_ + kk[i]) * (C_ / 4);
        f32x4* o4 = out4 + (size_t)(base + i) * (C_ / 4);
        #pragma unroll
        for (int j = 0; j < 3; ++j) {
            f32x4 v = a4[lane + 64 * j];
            v *= sc[i];
            __builtin_nontemporal_store(v, &o4[lane + 64 * j]);
        }
    }
}

extern "C" void kernel_launch(void* const* d_in, const int* in_sizes, int n_in,
                              void* d_out, int out_size, void* d_ws, size_t ws_size,
                              hipStream_t stream) {
    const float* g_feat = (const float*)d_in[0];
    const float* feat   = (const float*)d_in[1];
    // d_in[2] = tau: positive scale, numerically irrelevant (attn == y_hard exactly)
    const float* text   = (const float*)d_in[3];
    float* out = (float*)d_out;

    char* ws = (char*)d_ws;
    double* logits = (double*)(ws + 0);              // 256000 B
    float*  agg    = (float*) (ws + 262144);         // 1966080 B
    int*    sel    = (int*)   (ws + 2228224);        // 2560 B
    int*    cnt    = (int*)   (ws + 2230784);        // 2560 B
    int*    flagc  = (int*)   (ws + 2233344);        // 64 B
    int*    flagl  = (int*)   (ws + 2233408);        // 65536 B
    int*    kidx   = (int*)   (ws + 2301504);        // 524288 B

    k1_logits<<<dim3(32, 250), 256, 0, stream>>>(g_feat, text, logits, cnt, flagc);
    k1b_topk<<<32, 256, 0, stream>>>(logits, text, agg, sel);
    k2_argmax<<<32 * 16, 256, 0, stream>>>(feat, agg, kidx, cnt, flagc, flagl);
    k25_refine<<<64, 256, 0, stream>>>(feat, agg, kidx, cnt, flagc, flagl);
    k4_out<<<2048, 256, 0, stream>>>(agg, cnt, kidx, out);
}

// Round 4
// 299.609 us; speedup vs baseline: 1.3926x; 1.0160x over previous
//
#include <hip/hip_runtime.h>
#include <cfloat>

#define B_ 32
#define N_ 4096
#define C_ 768
#define T_ 1000
#define K_ 20

#define PXB 256           // pixels per k2 block
#define PHC 16            // floats per c-phase (64 B per px per phase)
#define NPH (C_/PHC)      // 48 phases
#define GAP_TH 1e-3f
#define MAXF 16384

typedef float f32x4 __attribute__((ext_vector_type(4)));

// ---------------- K1a: vg_logit in fp64 (+ zero counters) ----------------
__global__ __launch_bounds__(256) void k1_logits(const float* __restrict__ g_feat,
                                                 const float* __restrict__ text,
                                                 double* __restrict__ logits,
                                                 int* __restrict__ cnt,
                                                 int* __restrict__ flagcnt) {
    int b = blockIdx.x;
    int wid = threadIdx.x >> 6, lane = threadIdx.x & 63;
    int t = blockIdx.y * 4 + wid;           // grid.y = 250 -> t in [0,1000)
    if (b == 0 && blockIdx.y == 0) {
        for (int i = threadIdx.x; i < B_ * K_; i += 256) cnt[i] = 0;
        if (threadIdx.x == 0) flagcnt[0] = 0;
    }
    const float* g = g_feat + b * C_;
    const float* e = text + t * C_;
    double s = 0.0;
    #pragma unroll
    for (int j = 0; j < 12; ++j) {
        int c = lane + 64 * j;
        s += (double)g[c] * (double)e[c];
    }
    #pragma unroll
    for (int m = 32; m; m >>= 1) s += __shfl_xor(s, m);
    if (lane == 0) logits[b * T_ + t] = s;
}

// ---------------- K1b: top-20 per batch (1-wave shuffle select) + gather ----------------
__global__ __launch_bounds__(256) void k1b_topk(const double* __restrict__ logits,
                                                const float* __restrict__ text,
                                                float* __restrict__ agg,
                                                int* __restrict__ sel) {
    __shared__ int ssel[K_];
    int b = blockIdx.x, tid = threadIdx.x, lane = tid & 63;
    if (tid < 64) {
        double v[16];
        #pragma unroll
        for (int j = 0; j < 16; ++j) {
            int t = lane + 64 * j;
            v[j] = (t < T_) ? logits[b * T_ + t] : -DBL_MAX;
        }
        for (int it = 0; it < K_; ++it) {
            double bv = -DBL_MAX; int bi = 0x7fffffff;
            #pragma unroll
            for (int j = 0; j < 16; ++j) {
                int t = lane + 64 * j;
                if (v[j] > bv) { bv = v[j]; bi = t; }
            }
            #pragma unroll
            for (int m = 32; m; m >>= 1) {
                double ov = __shfl_xor(bv, m); int oi = __shfl_xor(bi, m);
                if (ov > bv || (ov == bv && oi < bi)) { bv = ov; bi = oi; }
            }
            if (lane == 0) ssel[it] = bi;
            #pragma unroll
            for (int j = 0; j < 16; ++j) {
                int t = lane + 64 * j;
                if (t == bi) v[j] = -DBL_MAX;
            }
        }
    }
    __syncthreads();
    if (tid < K_) sel[b * K_ + tid] = ssel[tid];
    for (int i = tid; i < K_ * C_; i += 256) {
        int j = i / C_, c = i - j * C_;
        agg[b * K_ * C_ + i] = text[ssel[j] * C_ + c];
    }
}

// ---------------- K2: per-pixel argmax, 2 px/thread, 2-deep pipelined staging ----------------
// 128 threads = 2 waves; 256 px/block; per phase per wave: 8 f-loads + 1 e-load
// via global_load_lds; triple buffer; counted s_waitcnt vmcnt(18) keeps 2 stages
// in flight across raw s_barriers. f chunks stored at phys = c ^ ((c>>3)&7)
// (16B-chunk XOR permutation: conflict-free ds_read_b128, linear LDS for DMA).
__global__ __launch_bounds__(128) void k2_argmax(const float* __restrict__ feat,
                                                 const float* __restrict__ agg,
                                                 int* __restrict__ kidx,
                                                 int* __restrict__ cnt,
                                                 int* __restrict__ flagcnt,
                                                 int* __restrict__ flaglist) {
    __shared__ float fbuf[3][PXB * PHC];      // 3 x 16 KB
    __shared__ float ebuf[3][512];            // 3 x 2 KB (128 chunks)
    __shared__ int scnt[K_];
    int bx = blockIdx.x;
    int b = bx >> 4, tile = bx & 15;
    int n0 = tile * PXB;
    int tid = threadIdx.x, wid = tid >> 6, lane = tid & 63;
    if (tid < K_) scnt[tid] = 0;
    __syncthreads();

    const float* fb = feat + ((size_t)b * N_ + n0) * C_;
    const float* eb = agg + b * (K_ * C_);

    // e-chunk this lane stages (80 chunks of 16B per phase; clamp tail)
    int se = wid * 64 + lane;
    int ce = se < 80 ? se : 79;
    const float* esrc = eb + (ce >> 2) * C_ + (ce & 3) * 4;

    auto stage = [&](int p, int bufi) {
        #pragma unroll
        for (int ii = 0; ii < 8; ++ii) {
            int s = (wid * 8 + ii) * 64 + lane;       // phys 16B slot
            int c = s ^ ((s >> 3) & 7);               // logical chunk
            int px = c >> 2, j = c & 3;
            const float* g = fb + (size_t)px * C_ + p * PHC + j * 4;
            float* d = &fbuf[bufi][(wid * 8 + ii) * 256];  // wave-uniform; HW adds lane*16
            __builtin_amdgcn_global_load_lds((const __attribute__((address_space(1))) void*)g,
                                             (__attribute__((address_space(3))) void*)d, 16, 0, 0);
        }
        {
            const float* g = esrc + p * PHC;
            float* d = &ebuf[bufi][wid * 256];
            __builtin_amdgcn_global_load_lds((const __attribute__((address_space(1))) void*)g,
                                             (__attribute__((address_space(3))) void*)d, 16, 0, 0);
        }
    };

    float acc0[K_], acc1[K_];
    #pragma unroll
    for (int k = 0; k < K_; ++k) { acc0[k] = 0.f; acc1[k] = 0.f; }

    stage(0, 0);
    stage(1, 1);

    int p0 = tid, p1 = tid + 128;                     // this thread's two pixels
    #pragma unroll 1
    for (int p = 0; p < NPH; ++p) {
        int bufi = p % 3;
        if (p + 2 < NPH) {
            stage(p + 2, (p + 2) % 3);
            asm volatile("s_waitcnt vmcnt(18)" ::: "memory");   // phase p's 9 landed
        } else if (p + 1 < NPH) {
            asm volatile("s_waitcnt vmcnt(9)" ::: "memory");
        } else {
            asm volatile("s_waitcnt vmcnt(0)" ::: "memory");
        }
        asm volatile("s_barrier" ::: "memory");

        const float* fB = fbuf[bufi];
        const float* eB = ebuf[bufi];
        f32x4 F0[4], F1[4];
        #pragma unroll
        for (int j = 0; j < 4; ++j) {
            int c0 = p0 * 4 + j, h0 = c0 ^ ((c0 >> 3) & 7);
            F0[j] = *(const f32x4*)(fB + h0 * 4);
            int c1 = p1 * 4 + j, h1 = c1 ^ ((c1 >> 3) & 7);
            F1[j] = *(const f32x4*)(fB + h1 * 4);
        }
        #pragma unroll
        for (int k = 0; k < K_; ++k) {
            float a0 = acc0[k], a1 = acc1[k];
            #pragma unroll
            for (int j = 0; j < 4; ++j) {
                f32x4 e = *(const f32x4*)(eB + (k * 4 + j) * 4);  // broadcast
                a0 = fmaf(F0[j].x, e.x, a0); a0 = fmaf(F0[j].y, e.y, a0);
                a0 = fmaf(F0[j].z, e.z, a0); a0 = fmaf(F0[j].w, e.w, a0);
                a1 = fmaf(F1[j].x, e.x, a1); a1 = fmaf(F1[j].y, e.y, a1);
                a1 = fmaf(F1[j].z, e.z, a1); a1 = fmaf(F1[j].w, e.w, a1);
            }
            acc0[k] = a0; acc1[k] = a1;
        }
        asm volatile("s_barrier" ::: "memory");       // buf reuse protection
    }

    // epilogue: top-2 scan for both pixels (first-max-wins == jnp.argmax)
    #pragma unroll
    for (int q = 0; q < 2; ++q) {
        float* acc = q ? acc1 : acc0;
        float m1 = acc[0]; int i1 = 0; float m2 = -FLT_MAX;
        #pragma unroll
        for (int k = 1; k < K_; ++k) {
            float v = acc[k];
            if (v > m1) { m2 = m1; m1 = v; i1 = k; }
            else if (v > m2) m2 = v;
        }
        int n = n0 + tid + q * 128;
        kidx[b * N_ + n] = i1;
        atomicAdd(&scnt[i1], 1);
        if (m1 - m2 < GAP_TH) {
            int pos = atomicAdd(flagcnt, 1);
            if (pos < MAXF) flaglist[pos] = b * N_ + n;
        }
    }
    __syncthreads();
    if (tid < K_) atomicAdd(&cnt[b * K_ + tid], scnt[tid]);
}

// ---------------- K2.5: fp64 re-decision for knife-edge pixels ----------------
__global__ __launch_bounds__(256) void k25_refine(const float* __restrict__ feat,
                                                  const float* __restrict__ agg,
                                                  int* __restrict__ kidx,
                                                  int* __restrict__ cnt,
                                                  const int* __restrict__ flagcnt,
                                                  const int* __restrict__ flaglist) {
    int wid = threadIdx.x >> 6, lane = threadIdx.x & 63;
    int wg = blockIdx.x * 4 + wid;
    int nf = flagcnt[0]; if (nf > MAXF) nf = MAXF;
    for (int e = wg; e < nf; e += gridDim.x * 4) {
        int pix = flaglist[e];
        int b = pix >> 12;
        const float* fr = feat + (size_t)pix * C_;
        const float* ebase = agg + b * K_ * C_;
        double fd[12];
        #pragma unroll
        for (int j = 0; j < 12; ++j) fd[j] = (double)fr[lane + 64 * j];
        double best = -DBL_MAX; int bi = 0;
        for (int k = 0; k < K_; ++k) {
            const float* er = ebase + k * C_;
            double s = 0.0;
            #pragma unroll
            for (int j = 0; j < 12; ++j) s += fd[j] * (double)er[lane + 64 * j];
            #pragma unroll
            for (int m = 32; m; m >>= 1) s += __shfl_xor(s, m);
            if (s > best) { best = s; bi = k; }
        }
        if (lane == 0) {
            int old = kidx[pix];
            if (old != bi) {
                kidx[pix] = bi;
                atomicSub(&cnt[b * K_ + old], 1);
                atomicAdd(&cnt[b * K_ + bi], 1);
            }
        }
    }
}

// ---------------- K4: broadcast-write output (8 px/wave) ----------------
__global__ __launch_bounds__(256) void k4_out(const float* __restrict__ agg,
                                              const int* __restrict__ cnt,
                                              const int* __restrict__ kidx,
                                              float* __restrict__ out) {
    int wid = threadIdx.x >> 6, lane = threadIdx.x & 63;
    int wg = blockIdx.x * 4 + wid;          // 16384 waves, 8 px each
    int base = wg * 8;
    int b = base >> 12;                     // wave-uniform (8 | 4096)
    int kk[8];
    #pragma unroll
    for (int i = 0; i < 8; ++i) kk[i] = kidx[base + i];
    float sc[8];
    #pragma unroll
    for (int i = 0; i < 8; ++i) sc[i] = 1.0f / ((float)cnt[b * K_ + kk[i]] + 1.0f);
    const f32x4* agg4 = (const f32x4*)agg;
    f32x4* out4 = (f32x4*)out;
    #pragma unroll
    for (int i = 0; i < 8; ++i) {
        const f32x4* a4 = agg4 + (size_t)(b * K_ + kk[i]) * (C_ / 4);
        f32x4* o4 = out4 + (size_t)(base + i) * (C_ / 4);
        #pragma unroll
        for (int j = 0; j < 3; ++j) {
            f32x4 v = a4[lane + 64 * j];
            v *= sc[i];
            __builtin_nontemporal_store(v, &o4[lane + 64 * j]);
        }
    }
}

extern "C" void kernel_launch(void* const* d_in, const int* in_sizes, int n_in,
                              void* d_out, int out_size, void* d_ws, size_t ws_size,
                              hipStream_t stream) {
    const float* g_feat = (const float*)d_in[0];
    const float* feat   = (const float*)d_in[1];
    // d_in[2] = tau: positive scale, numerically irrelevant (attn == y_hard exactly)
    const float* text   = (const float*)d_in[3];
    float* out = (float*)d_out;

    char* ws = (char*)d_ws;
    double* logits = (double*)(ws + 0);              // 256000 B
    float*  agg    = (float*) (ws + 262144);         // 1966080 B
    int*    sel    = (int*)   (ws + 2228224);        // 2560 B
    int*    cnt    = (int*)   (ws + 2230784);        // 2560 B
    int*    flagc  = (int*)   (ws + 2233344);        // 64 B
    int*    flagl  = (int*)   (ws + 2233408);        // 65536 B
    int*    kidx   = (int*)   (ws + 2301504);        // 524288 B

    k1_logits<<<dim3(32, 250), 256, 0, stream>>>(g_feat, text, logits, cnt, flagc);
    k1b_topk<<<32, 256, 0, stream>>>(logits, text, agg, sel);
    k2_argmax<<<32 * 16, 128, 0, stream>>>(feat, agg, kidx, cnt, flagc, flagl);
    k25_refine<<<64, 256, 0, stream>>>(feat, agg, kidx, cnt, flagc, flagl);
    k4_out<<<4096, 256, 0, stream>>>(agg, cnt, kidx, out);
}